// Round 15
// baseline (726.495 us; speedup 1.0000x reference)
//
#include <hip/hip_runtime.h>
#include <hip/hip_bf16.h>

// ---------- types ----------
typedef __attribute__((ext_vector_type(8))) short  bf16x8s;   // bf16 bit-patterns
typedef __attribute__((ext_vector_type(4))) float  f32x4;

#define MFMA_BF(a,b,c) __builtin_amdgcn_mfma_f32_16x16x32_bf16(a,b,c,0,0,0)

__device__ __forceinline__ unsigned short f2bf(float f){
  unsigned int u = __builtin_bit_cast(unsigned int, f);
  u += 0x7FFFu + ((u >> 16) & 1u);            // RNE
  return (unsigned short)(u >> 16);
}
__device__ __forceinline__ float bf2f(unsigned short h){
  return __builtin_bit_cast(float, (unsigned int)h << 16);
}

// ---------- problem sizes ----------
#define LL   2048
#define DD   512
#define HH   8
#define CC   192          // 3*64 per-head contraction length
#define OUT0 12582912     // f32 elems of 'out' before attn region
#define L3V  6144         // L*3
#define SCL  0.18033688011112042f   // 0.125 * log2(e)

// ---------- ws layout (bytes) ----------
#define QH_OFF   0u           // [32][2048][192] bf16
#define KH_OFF   25165824u    // [32][2048][192] bf16
#define VT_OFF   50331648u    // [32][192][2048] bf16  (V transposed for MFMA PV)
#define OH_OFF   75497472u    // [32][2048][192] bf16
#define WB_OFF   100663296u   // 4x[512*512] bf16 (Wq pre-scaled by SCL)
#define RINV_OFF 102760448u   // [65536] f32
#define WS_NEEDED 103022592u

// ---------- kernel 0: weight prep ----------
__global__ __launch_bounds__(256) void k_prep_w(
    const float* __restrict__ Wq, const float* __restrict__ Wk,
    const float* __restrict__ Wv, const float* __restrict__ Wo,
    unsigned short* __restrict__ Wb)
{
  int i = blockIdx.x*256 + threadIdx.x;           // grid 1024 -> 262144
  Wb[i]           = f2bf(Wq[i]*SCL);
  Wb[262144 + i]  = f2bf(Wk[i]);
  Wb[524288 + i]  = f2bf(Wv[i]);
  Wb[786432 + i]  = f2bf(Wo[i]);
}

// ---------- kernel 1: fused QKV projection, LDS-staged W with prefetch ----------
// grid (384 rowTiles, 2 nHalf, 3 tensor), 256 thr. Block tile 64(M) x 256(N).
__global__ __launch_bounds__(256, 3) void k_proj_qkv(
    const float* __restrict__ xq, const float* __restrict__ xk, const float* __restrict__ xv,
    const unsigned short* __restrict__ Wb,
    unsigned short* __restrict__ Qh, unsigned short* __restrict__ Kh,
    unsigned short* __restrict__ Vt)
{
  const int t = blockIdx.z;
  const float* __restrict__ x = (t==0) ? xq : ((t==1) ? xk : xv);
  const unsigned short* __restrict__ W = Wb + t*262144;
  const int rowBase = blockIdx.x*64;
  const int nBase   = blockIdx.y*256;
  const int tid = threadIdx.x, w = tid>>6, l = tid&63, g = l>>4, li = l&15;

  __shared__ unsigned short Wlds[256*40];         // 20,480 B (stride 40 = odd 16B multiple)
  __shared__ unsigned short Tl[64*65];            // V-transpose staging (t==2 only)

  const int arow = rowBase + w*16 + li;           // A row = lane&15
  const float* __restrict__ xrow = x + (size_t)arow*DD;

  f32x4 acc[16];
  #pragma unroll
  for (int nt = 0; nt < 16; ++nt) acc[nt] = (f32x4){0,0,0,0};

  bf16x8s wreg[4];
  #pragma unroll
  for (int i = 0; i < 4; ++i){
    const int f = i*256 + tid, r = f>>2, c8 = f&3;
    wreg[i] = *(const bf16x8s*)(W + (size_t)(nBase + r)*DD + c8*8);
  }
  float4 xa = *(const float4*)(xrow + g*8);
  float4 xb = *(const float4*)(xrow + g*8 + 4);

  for (int kk = 0; kk < 16; ++kk){
    __syncthreads();                              // prior LDS readers done
    #pragma unroll
    for (int i = 0; i < 4; ++i){
      const int f = i*256 + tid, r = f>>2, c8 = f&3;
      *(bf16x8s*)(Wlds + r*40 + c8*8) = wreg[i];
    }
    __syncthreads();

    bf16x8s a;
    a[0]=(short)f2bf(xa.x); a[1]=(short)f2bf(xa.y); a[2]=(short)f2bf(xa.z); a[3]=(short)f2bf(xa.w);
    a[4]=(short)f2bf(xb.x); a[5]=(short)f2bf(xb.y); a[6]=(short)f2bf(xb.z); a[7]=(short)f2bf(xb.w);

    if (kk < 15){                                 // prefetch next K-slice
      const int k0n = (kk+1)*32;
      #pragma unroll
      for (int i = 0; i < 4; ++i){
        const int f = i*256 + tid, r = f>>2, c8 = f&3;
        wreg[i] = *(const bf16x8s*)(W + (size_t)(nBase + r)*DD + k0n + c8*8);
      }
      xa = *(const float4*)(xrow + k0n + g*8);
      xb = *(const float4*)(xrow + k0n + g*8 + 4);
    }

    __builtin_amdgcn_s_setprio(1);
    #pragma unroll
    for (int nt = 0; nt < 16; ++nt){
      bf16x8s b = *(const bf16x8s*)(Wlds + (nt*16 + li)*40 + g*8);
      acc[nt] = MFMA_BF(a, b, acc[nt]);
    }
    __builtin_amdgcn_s_setprio(0);
  }

  if (t == 2){
    const int b    = rowBase / L3V;
    const int rloc = rowBase - b*L3V;             // batch-local row offset
    for (int hb = 0; hb < 4; ++hb){
      __syncthreads();                            // Tl reuse from previous head
      #pragma unroll
      for (int nt2 = 0; nt2 < 4; ++nt2)
        #pragma unroll
        for (int j = 0; j < 4; ++j)
          Tl[(w*16 + g*4 + j)*65 + nt2*16 + li] = f2bf(acc[hb*4 + nt2][j]);
      __syncthreads();
      if (tid < 192){
        const int v = tid >> 6, e = tid & 63;
        const int ls0 = (rloc - v + 2)/3;
        const int ls1 = (rloc + 63 - v)/3;        // inclusive
        const int hg  = (nBase >> 6) + hb;        // global head
        unsigned short* __restrict__ dst = Vt + ((size_t)((b*HH + hg)*CC + v*64 + e))*LL;
        for (int ls = ls0; ls <= ls1; ++ls){
          const int ml = 3*ls + v - rloc;
          dst[ls] = Tl[ml*65 + e];
        }
      }
    }
  } else {
    unsigned short* __restrict__ P = (t==0) ? Qh : Kh;
    #pragma unroll
    for (int nt = 0; nt < 16; ++nt){
      #pragma unroll
      for (int j = 0; j < 4; ++j){
        const int m  = rowBase + w*16 + g*4 + j;  // D row = (lane>>4)*4 + j
        const int d  = nBase + nt*16 + li;        // D col = lane&15
        const int b  = m / L3V;
        const int rm = m - b*L3V;
        const int ls = rm / 3;
        const int v  = rm - ls*3;
        const int h  = d >> 6, e = d & 63;
        P[((size_t)(b*HH + h)*LL + ls)*CC + v*64 + e] = f2bf(acc[nt][j]);
      }
    }
  }
}

// ---------- kernel 2: fused attention (r12 + Plds-aliased-into-Klds => 3 blocks/CU) ----------
// grid 1024 linear -> (xcd = bid&7 owns bh in [xcd*4, xcd*4+4), qt-major within bh).
// 256 thr = 4 waves; wave owns 16 q-rows; S-tile = 64. K/V LDS-staged, reg-prefetched.
// Plds reuses Klds's first 9,216B (disjoint lifetime; barrier between QK^T and exp).
// LDS total 53,248B -> 3 blocks/CU (was 62.5KB -> 2).
__global__ __launch_bounds__(256, 3) void k_attn(
    const unsigned short* __restrict__ Qh, const unsigned short* __restrict__ Kh,
    const unsigned short* __restrict__ Vt,
    float* __restrict__ attnp, unsigned short* __restrict__ Oh,
    float* __restrict__ rinvArr)
{
  const int bid  = blockIdx.x;
  const int xcd  = bid & 7, slot = bid >> 3;      // slot 0..127
  const int bh   = xcd*4 + (slot >> 5);           // 4 bh per XCD, qt-major
  const int qt   = slot & 31;
  const int tid = threadIdx.x, w = tid>>6, l = tid&63, g = l>>4, li = l&15;

  const unsigned short* __restrict__ Q = Qh + (size_t)bh*LL*CC;
  const unsigned short* __restrict__ K = Kh + (size_t)bh*LL*CC;
  const unsigned short* __restrict__ V = Vt + (size_t)bh*CC*LL;
  // bf16 view of this block's 64 attn rows; row r's payload = first 4096B of its 8KB slot
  unsigned short* __restrict__ A16 =
      (unsigned short*)(attnp + (size_t)bh*LL*LL + (size_t)(qt*64)*LL);

  // padded strides: K 200 elems (400B), V 72 elems (144B) — odd 16B multiples
  __shared__ unsigned short Klds[64*200];   // 25,600 B; first 9,216B double as Plds
  __shared__ unsigned short Vlds[192*72];   // 27,648 B
  unsigned short* __restrict__ Plds = Klds; // alias — lifetimes separated by barrier

  // Q fragments for this wave's 16 rows (K=192 -> 6 k-steps)
  bf16x8s aq[6];
  const unsigned short* __restrict__ qrow = Q + (size_t)(qt*64 + w*16 + li)*CC;
  #pragma unroll
  for (int ks = 0; ks < 6; ++ks) aq[ks] = *(const bf16x8s*)(qrow + ks*32 + g*8);

  f32x4 oacc[12];
  #pragma unroll
  for (int ct = 0; ct < 12; ++ct) oacc[ct] = (f32x4){0,0,0,0};
  float ssum[4] = {0.f,0.f,0.f,0.f};

  // staging registers: 6x16B K + 6x16B V per thread
  bf16x8s kreg[6], vreg[6];
  #pragma unroll
  for (int i = 0; i < 6; ++i){
    const int f = i*256 + tid;
    kreg[i] = *(const bf16x8s*)(K + (size_t)f*8);
    vreg[i] = *(const bf16x8s*)(V + (size_t)(f>>3)*LL + (f&7)*8);
  }

  for (int st = 0; st < 32; ++st){
    __syncthreads();                       // prev iter's Plds/Vlds readers done
    #pragma unroll
    for (int i = 0; i < 6; ++i){
      const int f  = i*256 + tid;
      const int kr = f / 24, ksg = f - kr*24;
      *(bf16x8s*)(Klds + kr*200 + ksg*8)       = kreg[i];
      *(bf16x8s*)(Vlds + (f>>3)*72 + (f&7)*8)  = vreg[i];
    }
    __syncthreads();
    if (st < 31){                          // prefetch next tile; hides under compute
      #pragma unroll
      for (int i = 0; i < 6; ++i){
        const int f = i*256 + tid;
        kreg[i] = *(const bf16x8s*)(K + (size_t)(st+1)*12288 + (size_t)f*8);
        vreg[i] = *(const bf16x8s*)(V + (size_t)(f>>3)*LL + (st+1)*64 + (f&7)*8);
      }
    }

    // --- QK^T: 16x64 scores, K=192 (B-frags from LDS) ---
    f32x4 sc[4] = { {0,0,0,0},{0,0,0,0},{0,0,0,0},{0,0,0,0} };
    __builtin_amdgcn_s_setprio(1);
    #pragma unroll
    for (int ks = 0; ks < 6; ++ks){
      #pragma unroll
      for (int nt = 0; nt < 4; ++nt){
        bf16x8s b = *(const bf16x8s*)(Klds + (nt*16 + li)*200 + ks*32 + g*8);
        sc[nt] = MFMA_BF(aq[ks], b, sc[nt]);
      }
    }
    __builtin_amdgcn_s_setprio(0);

    __syncthreads();                       // ALL waves done reading Klds before Plds writes

    // --- P = exp2(sc - 8): f32 sum, bf16 -> Plds (feeds PV and the global store) ---
    #pragma unroll
    for (int nt = 0; nt < 4; ++nt){
      #pragma unroll
      for (int j = 0; j < 4; ++j){
        float p = exp2f(sc[nt][j] - 8.0f);
        ssum[j] += p;
        Plds[(w*16 + g*4 + j)*72 + nt*16 + li] = f2bf(p);
      }
    }

    // --- PV: O[16,192] += P[16,64] * V[64,192] (V-frags from LDS) ---
    __builtin_amdgcn_s_setprio(1);
    #pragma unroll
    for (int kkk = 0; kkk < 2; ++kkk){
      bf16x8s pa = *(const bf16x8s*)(Plds + (w*16 + li)*72 + kkk*32 + g*8);
      #pragma unroll
      for (int ct = 0; ct < 12; ++ct){
        bf16x8s bv = *(const bf16x8s*)(Vlds + (ct*16 + li)*72 + kkk*32 + g*8);
        oacc[ct] = MFMA_BF(pa, bv, oacc[ct]);
      }
    }
    __builtin_amdgcn_s_setprio(0);

    // --- coalesced bf16 P store (wave-private rows; Plds stable until next staging) ---
    #pragma unroll
    for (int u = 0; u < 2; ++u){
      const int c  = u*64 + l;             // 0..127
      const int r  = c >> 3;               // wave-local row 0..15
      const int c8 = c & 7;
      bf16x8s pv = *(const bf16x8s*)(Plds + (w*16 + r)*72 + c8*8);
      *(bf16x8s*)(A16 + (size_t)(w*16 + r)*4096 + st*64 + c8*8) = pv;
    }
  }

  // row sums -> rinv (butterfly within 16-lane groups)
  float rinv[4];
  #pragma unroll
  for (int j = 0; j < 4; ++j){
    float s = ssum[j];
    s += __shfl_xor(s, 1); s += __shfl_xor(s, 2);
    s += __shfl_xor(s, 4); s += __shfl_xor(s, 8);
    rinv[j] = 1.0f / s;
  }
  if (li == 0){
    #pragma unroll
    for (int j = 0; j < 4; ++j)
      rinvArr[bh*LL + qt*64 + w*16 + g*4 + j] = rinv[j];
  }
  // normalized O -> Oh
  #pragma unroll
  for (int ct = 0; ct < 12; ++ct){
    #pragma unroll
    for (int j = 0; j < 4; ++j){
      const int row = qt*64 + w*16 + g*4 + j;
      Oh[((size_t)bh*LL + row)*CC + ct*16 + li] = f2bf(oacc[ct][j] * rinv[j]);
    }
  }
}

// ---------- kernel 2c: in-place expand bf16 P -> normalized f32 attn ----------
// grid (65536) rows, 256 thr. Load whole row to regs, barrier, NT f32 stores.
__global__ __launch_bounds__(256) void k_scale_attn(
    float* __restrict__ attnp, const float* __restrict__ rinvArr)
{
  const int row = blockIdx.x;
  const float r = rinvArr[row];
  float* __restrict__ rowp = attnp + (size_t)row*LL;
  const unsigned short* __restrict__ p16 = (const unsigned short*)rowp;

  bf16x8s v = *(const bf16x8s*)(p16 + threadIdx.x*8);   // elems t*8..t*8+7
  __syncthreads();                                      // all loads done before any store

  f32x4 o0, o1;
  o0[0] = bf2f((unsigned short)v[0])*r; o0[1] = bf2f((unsigned short)v[1])*r;
  o0[2] = bf2f((unsigned short)v[2])*r; o0[3] = bf2f((unsigned short)v[3])*r;
  o1[0] = bf2f((unsigned short)v[4])*r; o1[1] = bf2f((unsigned short)v[5])*r;
  o1[2] = bf2f((unsigned short)v[6])*r; o1[3] = bf2f((unsigned short)v[7])*r;
  f32x4* __restrict__ dst = (f32x4*)(rowp + threadIdx.x*8);
  __builtin_nontemporal_store(o0, dst);
  __builtin_nontemporal_store(o1, dst + 1);
}

// ---------- kernel 3: output projection, LDS-staged Wo with prefetch ----------
// grid (384, 2 nHalf), 256 thr. Block tile 64(M) x 256(N). Oh read exactly once.
__global__ __launch_bounds__(256, 3) void k_proj_out(
    const unsigned short* __restrict__ Oh, const unsigned short* __restrict__ Wo,
    float* __restrict__ out)
{
  const int rowBase = blockIdx.x*64;
  const int nBase   = blockIdx.y*256;
  const int tid = threadIdx.x, w = tid>>6, l = tid&63, g = l>>4, li = l&15;

  __shared__ unsigned short Wlds[256*40];         // 20,480 B

  const int m  = rowBase + w*16 + li;
  const int b  = m / L3V;
  const int rm = m - b*L3V;
  const int ls = rm / 3;
  const int v  = rm - ls*3;
  const unsigned short* __restrict__ obase = Oh + ((size_t)(b*HH)*LL + ls)*CC + v*64;

  f32x4 acc[16];
  #pragma unroll
  for (int nt = 0; nt < 16; ++nt) acc[nt] = (f32x4){0,0,0,0};

  bf16x8s wreg[4];
  #pragma unroll
  for (int i = 0; i < 4; ++i){
    const int f = i*256 + tid, r = f>>2, c8 = f&3;
    wreg[i] = *(const bf16x8s*)(Wo + (size_t)(nBase + r)*DD + c8*8);
  }
  bf16x8s acur = *(const bf16x8s*)(obase + g*8);  // kk=0

  for (int kk = 0; kk < 16; ++kk){
    __syncthreads();
    #pragma unroll
    for (int i = 0; i < 4; ++i){
      const int f = i*256 + tid, r = f>>2, c8 = f&3;
      *(bf16x8s*)(Wlds + r*40 + c8*8) = wreg[i];
    }
    __syncthreads();

    bf16x8s a = acur;
    if (kk < 15){
      const int kn = kk + 1;
      const int k0n = kn*32;
      acur = *(const bf16x8s*)(obase + (size_t)(kn>>1)*(LL*CC) + (kn&1)*32 + g*8);
      #pragma unroll
      for (int i = 0; i < 4; ++i){
        const int f = i*256 + tid, r = f>>2, c8 = f&3;
        wreg[i] = *(const bf16x8s*)(Wo + (size_t)(nBase + r)*DD + k0n + c8*8);
      }
    }

    __builtin_amdgcn_s_setprio(1);
    #pragma unroll
    for (int nt = 0; nt < 16; ++nt){
      bf16x8s bfr = *(const bf16x8s*)(Wlds + (nt*16 + li)*40 + g*8);
      acc[nt] = MFMA_BF(a, bfr, acc[nt]);
    }
    __builtin_amdgcn_s_setprio(0);
  }

  #pragma unroll
  for (int nt = 0; nt < 16; ++nt){
    #pragma unroll
    for (int j = 0; j < 4; ++j){
      const int mr = rowBase + w*16 + g*4 + j;
      out[(size_t)mr*DD + nBase + nt*16 + li] = acc[nt][j];
    }
  }
}

// ---------- launcher ----------
extern "C" void kernel_launch(void* const* d_in, const int* in_sizes, int n_in,
                              void* d_out, int out_size, void* d_ws, size_t ws_size,
                              hipStream_t stream)
{
  const float* xq = (const float*)d_in[0];
  const float* xk = (const float*)d_in[1];
  const float* xv = (const float*)d_in[2];
  const float* Wq = (const float*)d_in[3];
  const float* Wk = (const float*)d_in[4];
  const float* Wv = (const float*)d_in[5];
  const float* Wo = (const float*)d_in[6];

  if (ws_size < (size_t)WS_NEEDED) return;

  float* out  = (float*)d_out;          // reference outputs are float32
  float* attn = out + OUT0;             // [4,8,2048,2048] f32

  char* ws = (char*)d_ws;
  unsigned short* Qh = (unsigned short*)(ws + QH_OFF);
  unsigned short* Kh = (unsigned short*)(ws + KH_OFF);
  unsigned short* Vt = (unsigned short*)(ws + VT_OFF);
  unsigned short* Oh = (unsigned short*)(ws + OH_OFF);
  unsigned short* Wb = (unsigned short*)(ws + WB_OFF);
  float*        rinv = (float*)(ws + RINV_OFF);

  hipLaunchKernelGGL(k_prep_w,    dim3(1024),      dim3(256), 0, stream, Wq, Wk, Wv, Wo, Wb);
  hipLaunchKernelGGL(k_proj_qkv,  dim3(384, 2, 3), dim3(256), 0, stream, xq, xk, xv, Wb, Qh, Kh, Vt);
  hipLaunchKernelGGL(k_attn,      dim3(1024),      dim3(256), 0, stream, Qh, Kh, Vt, attn, Oh, rinv);
  hipLaunchKernelGGL(k_scale_attn,dim3(65536),     dim3(256), 0, stream, attn, rinv);
  hipLaunchKernelGGL(k_proj_out,  dim3(384, 2),    dim3(256), 0, stream, Oh, Wb + 786432, out);
}

// Round 16
// 497.279 us; speedup vs baseline: 1.4609x; 1.4609x over previous
//
#include <hip/hip_runtime.h>
#include <hip/hip_bf16.h>

// ---------- types ----------
typedef __attribute__((ext_vector_type(8))) short  bf16x8s;   // bf16 bit-patterns
typedef __attribute__((ext_vector_type(4))) float  f32x4;

#define MFMA_BF(a,b,c) __builtin_amdgcn_mfma_f32_16x16x32_bf16(a,b,c,0,0,0)

__device__ __forceinline__ unsigned short f2bf(float f){
  unsigned int u = __builtin_bit_cast(unsigned int, f);
  u += 0x7FFFu + ((u >> 16) & 1u);            // RNE
  return (unsigned short)(u >> 16);
}
__device__ __forceinline__ float bf2f(unsigned short h){
  return __builtin_bit_cast(float, (unsigned int)h << 16);
}

// ---------- problem sizes ----------
#define LL   2048
#define DD   512
#define HH   8
#define CC   192          // 3*64 per-head contraction length
#define OUT0 12582912     // f32 elems of 'out' before attn region
#define L3V  6144         // L*3
#define SCL  0.18033688011112042f   // 0.125 * log2(e)

// ---------- ws layout (bytes) ----------
#define QH_OFF   0u           // [32][2048][192] bf16
#define KH_OFF   25165824u    // [32][2048][192] bf16
#define VT_OFF   50331648u    // [32][192][2048] bf16  (V transposed for MFMA PV)
#define OH_OFF   75497472u    // [32][2048][192] bf16
#define WB_OFF   100663296u   // 4x[512*512] bf16 (Wq pre-scaled by SCL)
#define RINV_OFF 102760448u   // [65536] f32
#define WS_NEEDED 103022592u

// ---------- kernel 0: weight prep ----------
__global__ __launch_bounds__(256) void k_prep_w(
    const float* __restrict__ Wq, const float* __restrict__ Wk,
    const float* __restrict__ Wv, const float* __restrict__ Wo,
    unsigned short* __restrict__ Wb)
{
  int i = blockIdx.x*256 + threadIdx.x;           // grid 1024 -> 262144
  Wb[i]           = f2bf(Wq[i]*SCL);
  Wb[262144 + i]  = f2bf(Wk[i]);
  Wb[524288 + i]  = f2bf(Wv[i]);
  Wb[786432 + i]  = f2bf(Wo[i]);
}

// ---------- kernel 1: fused QKV projection, LDS-staged W with prefetch ----------
// grid (384 rowTiles, 2 nHalf, 3 tensor), 256 thr. Block tile 64(M) x 256(N).
__global__ __launch_bounds__(256, 3) void k_proj_qkv(
    const float* __restrict__ xq, const float* __restrict__ xk, const float* __restrict__ xv,
    const unsigned short* __restrict__ Wb,
    unsigned short* __restrict__ Qh, unsigned short* __restrict__ Kh,
    unsigned short* __restrict__ Vt)
{
  const int t = blockIdx.z;
  const float* __restrict__ x = (t==0) ? xq : ((t==1) ? xk : xv);
  const unsigned short* __restrict__ W = Wb + t*262144;
  const int rowBase = blockIdx.x*64;
  const int nBase   = blockIdx.y*256;
  const int tid = threadIdx.x, w = tid>>6, l = tid&63, g = l>>4, li = l&15;

  __shared__ unsigned short Wlds[256*40];         // 20,480 B (stride 40 = odd 16B multiple)
  __shared__ unsigned short Tl[64*65];            // V-transpose staging (t==2 only)

  const int arow = rowBase + w*16 + li;           // A row = lane&15
  const float* __restrict__ xrow = x + (size_t)arow*DD;

  f32x4 acc[16];
  #pragma unroll
  for (int nt = 0; nt < 16; ++nt) acc[nt] = (f32x4){0,0,0,0};

  bf16x8s wreg[4];
  #pragma unroll
  for (int i = 0; i < 4; ++i){
    const int f = i*256 + tid, r = f>>2, c8 = f&3;
    wreg[i] = *(const bf16x8s*)(W + (size_t)(nBase + r)*DD + c8*8);
  }
  float4 xa = *(const float4*)(xrow + g*8);
  float4 xb = *(const float4*)(xrow + g*8 + 4);

  for (int kk = 0; kk < 16; ++kk){
    __syncthreads();                              // prior LDS readers done
    #pragma unroll
    for (int i = 0; i < 4; ++i){
      const int f = i*256 + tid, r = f>>2, c8 = f&3;
      *(bf16x8s*)(Wlds + r*40 + c8*8) = wreg[i];
    }
    __syncthreads();

    bf16x8s a;
    a[0]=(short)f2bf(xa.x); a[1]=(short)f2bf(xa.y); a[2]=(short)f2bf(xa.z); a[3]=(short)f2bf(xa.w);
    a[4]=(short)f2bf(xb.x); a[5]=(short)f2bf(xb.y); a[6]=(short)f2bf(xb.z); a[7]=(short)f2bf(xb.w);

    if (kk < 15){                                 // prefetch next K-slice
      const int k0n = (kk+1)*32;
      #pragma unroll
      for (int i = 0; i < 4; ++i){
        const int f = i*256 + tid, r = f>>2, c8 = f&3;
        wreg[i] = *(const bf16x8s*)(W + (size_t)(nBase + r)*DD + k0n + c8*8);
      }
      xa = *(const float4*)(xrow + k0n + g*8);
      xb = *(const float4*)(xrow + k0n + g*8 + 4);
    }

    __builtin_amdgcn_s_setprio(1);
    #pragma unroll
    for (int nt = 0; nt < 16; ++nt){
      bf16x8s b = *(const bf16x8s*)(Wlds + (nt*16 + li)*40 + g*8);
      acc[nt] = MFMA_BF(a, b, acc[nt]);
    }
    __builtin_amdgcn_s_setprio(0);
  }

  if (t == 2){
    const int b    = rowBase / L3V;
    const int rloc = rowBase - b*L3V;             // batch-local row offset
    for (int hb = 0; hb < 4; ++hb){
      __syncthreads();                            // Tl reuse from previous head
      #pragma unroll
      for (int nt2 = 0; nt2 < 4; ++nt2)
        #pragma unroll
        for (int j = 0; j < 4; ++j)
          Tl[(w*16 + g*4 + j)*65 + nt2*16 + li] = f2bf(acc[hb*4 + nt2][j]);
      __syncthreads();
      if (tid < 192){
        const int v = tid >> 6, e = tid & 63;
        const int ls0 = (rloc - v + 2)/3;
        const int ls1 = (rloc + 63 - v)/3;        // inclusive
        const int hg  = (nBase >> 6) + hb;        // global head
        unsigned short* __restrict__ dst = Vt + ((size_t)((b*HH + hg)*CC + v*64 + e))*LL;
        for (int ls = ls0; ls <= ls1; ++ls){
          const int ml = 3*ls + v - rloc;
          dst[ls] = Tl[ml*65 + e];
        }
      }
    }
  } else {
    unsigned short* __restrict__ P = (t==0) ? Qh : Kh;
    #pragma unroll
    for (int nt = 0; nt < 16; ++nt){
      #pragma unroll
      for (int j = 0; j < 4; ++j){
        const int m  = rowBase + w*16 + g*4 + j;  // D row = (lane>>4)*4 + j
        const int d  = nBase + nt*16 + li;        // D col = lane&15
        const int b  = m / L3V;
        const int rm = m - b*L3V;
        const int ls = rm / 3;
        const int v  = rm - ls*3;
        const int h  = d >> 6, e = d & 63;
        P[((size_t)(b*HH + h)*LL + ls)*CC + v*64 + e] = f2bf(acc[nt][j]);
      }
    }
  }
}

// ---------- kernel 2: fused attention (r12-verified: 256 thr, XCD swizzle, bf16 P) ----------
// grid 1024 linear -> (xcd = bid&7 owns bh in [xcd*4, xcd*4+4), qt-major within bh).
// 256 thr = 4 waves; wave owns 16 q-rows; S-tile = 64. K/V LDS-staged, reg-prefetched.
// Unnormalized P stored as bf16 packed in the FIRST HALF of each attn row's f32 slot.
__global__ __launch_bounds__(256, 2) void k_attn(
    const unsigned short* __restrict__ Qh, const unsigned short* __restrict__ Kh,
    const unsigned short* __restrict__ Vt,
    float* __restrict__ attnp, unsigned short* __restrict__ Oh,
    float* __restrict__ rinvArr)
{
  const int bid  = blockIdx.x;
  const int xcd  = bid & 7, slot = bid >> 3;      // slot 0..127
  const int bh   = xcd*4 + (slot >> 5);           // 4 bh per XCD, qt-major
  const int qt   = slot & 31;
  const int tid = threadIdx.x, w = tid>>6, l = tid&63, g = l>>4, li = l&15;

  const unsigned short* __restrict__ Q = Qh + (size_t)bh*LL*CC;
  const unsigned short* __restrict__ K = Kh + (size_t)bh*LL*CC;
  const unsigned short* __restrict__ V = Vt + (size_t)bh*CC*LL;
  // bf16 view of this block's 64 attn rows; row r's payload = first 4096B of its 8KB slot
  unsigned short* __restrict__ A16 =
      (unsigned short*)(attnp + (size_t)bh*LL*LL + (size_t)(qt*64)*LL);

  // padded strides: K 200 elems (400B), V/P 72 elems (144B) — odd 16B multiples
  __shared__ unsigned short Klds[64*200];   // 25600 B
  __shared__ unsigned short Vlds[192*72];   // 27648 B
  __shared__ unsigned short Plds[64*72];    //  9216 B

  // Q fragments for this wave's 16 rows (K=192 -> 6 k-steps)
  bf16x8s aq[6];
  const unsigned short* __restrict__ qrow = Q + (size_t)(qt*64 + w*16 + li)*CC;
  #pragma unroll
  for (int ks = 0; ks < 6; ++ks) aq[ks] = *(const bf16x8s*)(qrow + ks*32 + g*8);

  f32x4 oacc[12];
  #pragma unroll
  for (int ct = 0; ct < 12; ++ct) oacc[ct] = (f32x4){0,0,0,0};
  float ssum[4] = {0.f,0.f,0.f,0.f};

  // staging registers: 6x16B K + 6x16B V per thread
  bf16x8s kreg[6], vreg[6];
  #pragma unroll
  for (int i = 0; i < 6; ++i){
    const int f = i*256 + tid;
    kreg[i] = *(const bf16x8s*)(K + (size_t)f*8);
    vreg[i] = *(const bf16x8s*)(V + (size_t)(f>>3)*LL + (f&7)*8);
  }

  for (int st = 0; st < 32; ++st){
    __syncthreads();                       // prior iteration's LDS readers done
    #pragma unroll
    for (int i = 0; i < 6; ++i){
      const int f  = i*256 + tid;
      const int kr = f / 24, ksg = f - kr*24;
      *(bf16x8s*)(Klds + kr*200 + ksg*8)       = kreg[i];
      *(bf16x8s*)(Vlds + (f>>3)*72 + (f&7)*8)  = vreg[i];
    }
    __syncthreads();
    if (st < 31){                          // prefetch next tile; hides under compute
      #pragma unroll
      for (int i = 0; i < 6; ++i){
        const int f = i*256 + tid;
        kreg[i] = *(const bf16x8s*)(K + (size_t)(st+1)*12288 + (size_t)f*8);
        vreg[i] = *(const bf16x8s*)(V + (size_t)(f>>3)*LL + (st+1)*64 + (f&7)*8);
      }
    }

    // --- QK^T: 16x64 scores, K=192 (B-frags from LDS) ---
    f32x4 sc[4] = { {0,0,0,0},{0,0,0,0},{0,0,0,0},{0,0,0,0} };
    __builtin_amdgcn_s_setprio(1);
    #pragma unroll
    for (int ks = 0; ks < 6; ++ks){
      #pragma unroll
      for (int nt = 0; nt < 4; ++nt){
        bf16x8s b = *(const bf16x8s*)(Klds + (nt*16 + li)*200 + ks*32 + g*8);
        sc[nt] = MFMA_BF(aq[ks], b, sc[nt]);
      }
    }
    __builtin_amdgcn_s_setprio(0);

    // --- P = exp2(sc - 8): f32 sum, bf16 -> LDS (feeds PV and the global store) ---
    #pragma unroll
    for (int nt = 0; nt < 4; ++nt){
      #pragma unroll
      for (int j = 0; j < 4; ++j){
        float p = exp2f(sc[nt][j] - 8.0f);
        ssum[j] += p;
        Plds[(w*16 + g*4 + j)*72 + nt*16 + li] = f2bf(p);
      }
    }

    // --- PV: O[16,192] += P[16,64] * V[64,192] (V-frags from LDS) ---
    __builtin_amdgcn_s_setprio(1);
    #pragma unroll
    for (int kkk = 0; kkk < 2; ++kkk){
      bf16x8s pa = *(const bf16x8s*)(Plds + (w*16 + li)*72 + kkk*32 + g*8);
      #pragma unroll
      for (int ct = 0; ct < 12; ++ct){
        bf16x8s bv = *(const bf16x8s*)(Vlds + (ct*16 + li)*72 + kkk*32 + g*8);
        oacc[ct] = MFMA_BF(pa, bv, oacc[ct]);
      }
    }
    __builtin_amdgcn_s_setprio(0);

    // --- coalesced bf16 P store (wave-private rows; Plds stable until next exp) ---
    #pragma unroll
    for (int u = 0; u < 2; ++u){
      const int c  = u*64 + l;             // 0..127
      const int r  = c >> 3;               // wave-local row 0..15
      const int c8 = c & 7;
      bf16x8s pv = *(const bf16x8s*)(Plds + (w*16 + r)*72 + c8*8);
      *(bf16x8s*)(A16 + (size_t)(w*16 + r)*4096 + st*64 + c8*8) = pv;
    }
  }

  // row sums -> rinv (butterfly within 16-lane groups)
  float rinv[4];
  #pragma unroll
  for (int j = 0; j < 4; ++j){
    float s = ssum[j];
    s += __shfl_xor(s, 1); s += __shfl_xor(s, 2);
    s += __shfl_xor(s, 4); s += __shfl_xor(s, 8);
    rinv[j] = 1.0f / s;
  }
  if (li == 0){
    #pragma unroll
    for (int j = 0; j < 4; ++j)
      rinvArr[bh*LL + qt*64 + w*16 + g*4 + j] = rinv[j];
  }
  // normalized O -> Oh
  #pragma unroll
  for (int ct = 0; ct < 12; ++ct){
    #pragma unroll
    for (int j = 0; j < 4; ++j){
      const int row = qt*64 + w*16 + g*4 + j;
      Oh[((size_t)bh*LL + row)*CC + ct*16 + li] = f2bf(oacc[ct][j] * rinv[j]);
    }
  }
}

// ---------- kernel 2c: in-place expand bf16 P -> normalized f32 attn ----------
// grid (65536) rows, 256 thr. Load whole row to regs, barrier, NT f32 stores.
__global__ __launch_bounds__(256) void k_scale_attn(
    float* __restrict__ attnp, const float* __restrict__ rinvArr)
{
  const int row = blockIdx.x;
  const float r = rinvArr[row];
  float* __restrict__ rowp = attnp + (size_t)row*LL;
  const unsigned short* __restrict__ p16 = (const unsigned short*)rowp;

  bf16x8s v = *(const bf16x8s*)(p16 + threadIdx.x*8);   // elems t*8..t*8+7
  __syncthreads();                                      // all loads done before any store

  f32x4 o0, o1;
  o0[0] = bf2f((unsigned short)v[0])*r; o0[1] = bf2f((unsigned short)v[1])*r;
  o0[2] = bf2f((unsigned short)v[2])*r; o0[3] = bf2f((unsigned short)v[3])*r;
  o1[0] = bf2f((unsigned short)v[4])*r; o1[1] = bf2f((unsigned short)v[5])*r;
  o1[2] = bf2f((unsigned short)v[6])*r; o1[3] = bf2f((unsigned short)v[7])*r;
  f32x4* __restrict__ dst = (f32x4*)(rowp + threadIdx.x*8);
  __builtin_nontemporal_store(o0, dst);
  __builtin_nontemporal_store(o1, dst + 1);
}

// ---------- kernel 3: output projection, LDS-staged Wo with prefetch ----------
// grid (384, 2 nHalf), 256 thr. Block tile 64(M) x 256(N). Oh read exactly once.
__global__ __launch_bounds__(256, 3) void k_proj_out(
    const unsigned short* __restrict__ Oh, const unsigned short* __restrict__ Wo,
    float* __restrict__ out)
{
  const int rowBase = blockIdx.x*64;
  const int nBase   = blockIdx.y*256;
  const int tid = threadIdx.x, w = tid>>6, l = tid&63, g = l>>4, li = l&15;

  __shared__ unsigned short Wlds[256*40];         // 20,480 B

  const int m  = rowBase + w*16 + li;
  const int b  = m / L3V;
  const int rm = m - b*L3V;
  const int ls = rm / 3;
  const int v  = rm - ls*3;
  const unsigned short* __restrict__ obase = Oh + ((size_t)(b*HH)*LL + ls)*CC + v*64;

  f32x4 acc[16];
  #pragma unroll
  for (int nt = 0; nt < 16; ++nt) acc[nt] = (f32x4){0,0,0,0};

  bf16x8s wreg[4];
  #pragma unroll
  for (int i = 0; i < 4; ++i){
    const int f = i*256 + tid, r = f>>2, c8 = f&3;
    wreg[i] = *(const bf16x8s*)(Wo + (size_t)(nBase + r)*DD + c8*8);
  }
  bf16x8s acur = *(const bf16x8s*)(obase + g*8);  // kk=0

  for (int kk = 0; kk < 16; ++kk){
    __syncthreads();
    #pragma unroll
    for (int i = 0; i < 4; ++i){
      const int f = i*256 + tid, r = f>>2, c8 = f&3;
      *(bf16x8s*)(Wlds + r*40 + c8*8) = wreg[i];
    }
    __syncthreads();

    bf16x8s a = acur;
    if (kk < 15){
      const int kn = kk + 1;
      const int k0n = kn*32;
      acur = *(const bf16x8s*)(obase + (size_t)(kn>>1)*(LL*CC) + (kn&1)*32 + g*8);
      #pragma unroll
      for (int i = 0; i < 4; ++i){
        const int f = i*256 + tid, r = f>>2, c8 = f&3;
        wreg[i] = *(const bf16x8s*)(Wo + (size_t)(nBase + r)*DD + k0n + c8*8);
      }
    }

    __builtin_amdgcn_s_setprio(1);
    #pragma unroll
    for (int nt = 0; nt < 16; ++nt){
      bf16x8s bfr = *(const bf16x8s*)(Wlds + (nt*16 + li)*40 + g*8);
      acc[nt] = MFMA_BF(a, bfr, acc[nt]);
    }
    __builtin_amdgcn_s_setprio(0);
  }

  #pragma unroll
  for (int nt = 0; nt < 16; ++nt){
    #pragma unroll
    for (int j = 0; j < 4; ++j){
      const int mr = rowBase + w*16 + g*4 + j;
      out[(size_t)mr*DD + nBase + nt*16 + li] = acc[nt][j];
    }
  }
}

// ---------- launcher ----------
extern "C" void kernel_launch(void* const* d_in, const int* in_sizes, int n_in,
                              void* d_out, int out_size, void* d_ws, size_t ws_size,
                              hipStream_t stream)
{
  const float* xq = (const float*)d_in[0];
  const float* xk = (const float*)d_in[1];
  const float* xv = (const float*)d_in[2];
  const float* Wq = (const float*)d_in[3];
  const float* Wk = (const float*)d_in[4];
  const float* Wv = (const float*)d_in[5];
  const float* Wo = (const float*)d_in[6];

  if (ws_size < (size_t)WS_NEEDED) return;

  float* out  = (float*)d_out;          // reference outputs are float32
  float* attn = out + OUT0;             // [4,8,2048,2048] f32

  char* ws = (char*)d_ws;
  unsigned short* Qh = (unsigned short*)(ws + QH_OFF);
  unsigned short* Kh = (unsigned short*)(ws + KH_OFF);
  unsigned short* Vt = (unsigned short*)(ws + VT_OFF);
  unsigned short* Oh = (unsigned short*)(ws + OH_OFF);
  unsigned short* Wb = (unsigned short*)(ws + WB_OFF);
  float*        rinv = (float*)(ws + RINV_OFF);

  hipLaunchKernelGGL(k_prep_w,    dim3(1024),      dim3(256), 0, stream, Wq, Wk, Wv, Wo, Wb);
  hipLaunchKernelGGL(k_proj_qkv,  dim3(384, 2, 3), dim3(256), 0, stream, xq, xk, xv, Wb, Qh, Kh, Vt);
  hipLaunchKernelGGL(k_attn,      dim3(1024),      dim3(256), 0, stream, Qh, Kh, Vt, attn, Oh, rinv);
  hipLaunchKernelGGL(k_scale_attn,dim3(65536),     dim3(256), 0, stream, attn, rinv);
  hipLaunchKernelGGL(k_proj_out,  dim3(384, 2),    dim3(256), 0, stream, Oh, Wb + 786432, out);
}